// Round 7
// baseline (1094.995 us; speedup 1.0000x reference)
//
#include <hip/hip_runtime.h>
#include <hip/hip_bf16.h>
#include <cmath>

// DXVAE: 7-node sequential graph GRU + VAE head, B=2048, H=1024. f32 I/O.
// R7: direct-register GEMM. Operands are K-major -> each lane's MFMA fragment
// is ONE aligned 16B contiguous global load. K-loop uses NAMED double-buffer
// fragment registers (a*/b* vs p*/q*, loop unrolled in pairs -> no runtime
// indexing -> no scratch spill, R5's killer). No LDS, no barriers in K-loop;
// compiler emits vmcnt(8)-style waits (AITER pattern). Per-wave tile 64x64
// (16 MFMA : 8 loads per K-step). GRU fused in epilogue via gate-interleaved
// W_aug (row=h*4+gate): acc -> LDS tile -> gather 4 gates -> h'.

typedef __hip_bfloat16 bf16;
typedef __attribute__((ext_vector_type(8))) short bf16x8;   // 8 bf16 (4 VGPRs)
typedef __attribute__((ext_vector_type(4))) float f32x4;    // C/D frag

constexpr int BATCH = 2048;
constexpr int HD    = 1024;
constexpr int LDA   = 1056;          // augmented A stride (1024 h + 32 x-pad)
constexpr size_t BH = (size_t)BATCH * HD;

__device__ __forceinline__ bf16  f2bf(float v){ return __float2bfloat16(v); }
__device__ __forceinline__ float sigm(float x){ return 1.0f/(1.0f+__expf(-x)); }

// 4 bf16 -> 4 f32 (exact: bits<<16)
__device__ __forceinline__ void ld4f(const bf16* p, float* o){
  ushort4 u = *reinterpret_cast<const ushort4*>(p);
  o[0] = __uint_as_float(((unsigned)u.x)<<16);
  o[1] = __uint_as_float(((unsigned)u.y)<<16);
  o[2] = __uint_as_float(((unsigned)u.z)<<16);
  o[3] = __uint_as_float(((unsigned)u.w)<<16);
}
__device__ __forceinline__ void st4bf(bf16* p, const float* v){
  bf16 o[4] = {f2bf(v[0]), f2bf(v[1]), f2bf(v[2]), f2bf(v[3])};
  *reinterpret_cast<ushort4*>(p) = *reinterpret_cast<const ushort4*>(o);
}

// ---------------------------------------------------------------------------
// Weight packing (once per launch)
// ---------------------------------------------------------------------------
// Gate-interleaved W_aug (4096 x 1056): row h*4+g.
// g0:[Whh_r|Wih_r] g1:[Whh_z|Wih_z] g2:[Whh_n|0] g3:[0|Wih_n]; x zero-padded.
__global__ __launch_bounds__(256) void pack_waug_i(
    const float* __restrict__ Whh, const float* __restrict__ Wih, int xw,
    bf16* __restrict__ out)
{
  int c = blockIdx.x;                 // 0..4095
  int h = c >> 2, g = c & 3;
  for (int ch = threadIdx.x; ch < 264; ch += 256){
    int f0 = ch*4;
    float v[4] = {0.f,0.f,0.f,0.f};
    if (f0 < 1024){
      if (g < 3){
        int src = (g==2) ? (2048+h) : (g*1024+h);
        const float4 t = *reinterpret_cast<const float4*>(Whh + (size_t)src*1024 + f0);
        v[0]=t.x; v[1]=t.y; v[2]=t.z; v[3]=t.w;
      }
    } else if (g != 2){
      int src = (g==0) ? h : (g==1) ? (1024+h) : (2048+h);
      int fx = f0 - 1024;
      #pragma unroll
      for (int j=0;j<4;++j) if (fx+j < xw) v[j] = Wih[(size_t)src*xw + fx + j];
    }
    st4bf(out + (size_t)c*LDA + f0, v);
  }
}

// Wgm (4096x1024) = [Wg[:,:1024]; Wg[:,1024:]; Wm[:,:1024]; Wm[:,1024:]]
__global__ __launch_bounds__(256) void pack_wgm(const float* __restrict__ Wg,
    const float* __restrict__ Wm, bf16* __restrict__ outW){
  int i = blockIdx.x*256 + threadIdx.x;          // < 4096*256
  int c = i >> 8, f0 = (i & 255)*4;
  int j = c >> 10, h = c & 1023;
  const float* src = (j < 2) ? Wg : Wm;
  float4 t = *reinterpret_cast<const float4*>(src + (size_t)h*2048 + ((j & 1) ? 1024 : 0) + f0);
  float v[4] = {t.x,t.y,t.z,t.w};
  st4bf(outW + (size_t)c*1024 + f0, v);
}

// Wms (512x1024) = [Wmu; Wstd]
__global__ __launch_bounds__(256) void pack_wms(const float* __restrict__ Wmu,
    const float* __restrict__ Wstd, bf16* __restrict__ outW){
  int i = blockIdx.x*256 + threadIdx.x;          // < 512*256
  int c = i >> 8, f0 = (i & 255)*4;
  const float* src = (c < 256) ? (Wmu + (size_t)c*1024) : (Wstd + (size_t)(c-256)*1024);
  float4 t = *reinterpret_cast<const float4*>(src + f0);
  float v[4] = {t.x,t.y,t.z,t.w};
  st4bf(outW + (size_t)c*1024 + f0, v);
}

// Xpad (7 x 2048 x 32): X[:,v,:27] zero-padded to 32, bf16
__global__ __launch_bounds__(256) void pack_xpad(const float* __restrict__ X,
    bf16* __restrict__ out){
  int i = blockIdx.x*256 + threadIdx.x;          // < 7*2048*32
  int f = i & 31, bv = i >> 5;
  int b = bv / 7, v = bv % 7;
  float val = (f < 27) ? X[((size_t)b*7 + v)*27 + f] : 0.f;
  out[((size_t)v*BATCH + b)*32 + f] = f2bf(val);
}
// XpadR (2048 x 32): X[:,0,:23] zero-padded, bf16
__global__ __launch_bounds__(256) void pack_xpr(const float* __restrict__ X,
    bf16* __restrict__ out){
  int i = blockIdx.x*256 + threadIdx.x;          // < 2048*32
  int f = i & 31, b = i >> 5;
  float val = (f < 23) ? X[(size_t)b*7*27 + f] : 0.f;
  out[(size_t)b*32 + f] = f2bf(val);
}

// ---------------------------------------------------------------------------
// Stage combine: Hin[b, 0:1024] = sum_{k>v} sigm(p*Pg1+s*Pg2+bg)*(p*Pm1+s*Pm2)
// Hin[b, 1024:1056] = x-tail. v==6: empty loop -> zeros + tail.
// ---------------------------------------------------------------------------
__global__ __launch_bounds__(256) void combine_k(
    const bf16* __restrict__ P, const int* __restrict__ adj,
    const float* __restrict__ bg, const bf16* __restrict__ tailsrc,
    bf16* __restrict__ Hin, int v)
{
  int t  = threadIdx.x;
  int b  = blockIdx.x*2 + (t>>7);
  int tl = t & 127;
  int h0 = tl*8;
  float acc[8] = {0,0,0,0,0,0,0,0};
  float bgv[8];
  { const float4 a = *reinterpret_cast<const float4*>(bg + h0);
    const float4 c = *reinterpret_cast<const float4*>(bg + h0 + 4);
    bgv[0]=a.x;bgv[1]=a.y;bgv[2]=a.z;bgv[3]=a.w;bgv[4]=c.x;bgv[5]=c.y;bgv[6]=c.z;bgv[7]=c.w; }
  for (int k=v+1;k<7;++k){
    bool p = adj[b*49 + k*7 + v] > 0;
    bool s = adj[b*49 + v*7 + k] > 0;
    if (!p && !s) continue;
    const bf16* base = P + (size_t)(k-1)*4*BH + (size_t)b*HD + h0;
    float g1[8], g2[8], m1[8], m2[8];
    ld4f(base,          g1); ld4f(base+4,        g1+4);
    ld4f(base+BH,       g2); ld4f(base+BH+4,     g2+4);
    ld4f(base+2*BH,     m1); ld4f(base+2*BH+4,   m1+4);
    ld4f(base+3*BH,     m2); ld4f(base+3*BH+4,   m2+4);
    #pragma unroll
    for (int u=0;u<8;++u){
      float gg = (p?g1[u]:0.f) + (s?g2[u]:0.f);
      float mm = (p?m1[u]:0.f) + (s?m2[u]:0.f);
      acc[u] += sigm(gg + bgv[u]) * mm;
    }
  }
  st4bf(Hin + (size_t)b*LDA + h0,     acc);
  st4bf(Hin + (size_t)b*LDA + h0 + 4, acc+4);
  if (tl < 4){   // x-tail: 32 elems per row, 4 threads x 8
    const ushort4* s0 = reinterpret_cast<const ushort4*>(tailsrc + (size_t)b*32 + tl*8);
    ushort4* d0 = reinterpret_cast<ushort4*>(Hin + (size_t)b*LDA + 1024 + tl*8);
    d0[0] = s0[0]; d0[1] = s0[1];
  }
}

// ---------------------------------------------------------------------------
// Direct-register GEMM: C = A(2048 x K) @ W^T. Per-wave 64x64 tile (4x4 MFMA,
// 16 MFMA : 8 direct 16B global frag loads per BK=32 step), named-register
// double buffer, no LDS/barriers in the K-loop. Block = 4 waves spanning
// 256 N-cols. Grid (M/64, N/256).
// MODE 0: gate-interleaved GRU (N=4096): epilogue h' via LDS gather.
// MODE 1: P-plane output (N=4096, plane-major rows)
// MODE 2: mu/std head (N=512, f32 out, bias+softplus)
// ---------------------------------------------------------------------------
#define LD8(dst, base, kk) dst = *reinterpret_cast<const bf16x8*>((base) + (kk))
#define LOADALL(x0,x1,x2,x3,y0,y1,y2,y3,kk) do{ \
  LD8(x0,pA0,kk); LD8(x1,pA1,kk); LD8(x2,pA2,kk); LD8(x3,pA3,kk); \
  LD8(y0,pB0,kk); LD8(y1,pB1,kk); LD8(y2,pB2,kk); LD8(y3,pB3,kk); }while(0)
#define MM(ar,bc,i,j) acc[i][j] = __builtin_amdgcn_mfma_f32_16x16x32_bf16(ar, bc, acc[i][j], 0,0,0)
#define MFMA16(x0,x1,x2,x3,y0,y1,y2,y3) do{ \
  MM(x0,y0,0,0); MM(x0,y1,0,1); MM(x0,y2,0,2); MM(x0,y3,0,3); \
  MM(x1,y0,1,0); MM(x1,y1,1,1); MM(x1,y2,1,2); MM(x1,y3,1,3); \
  MM(x2,y0,2,0); MM(x2,y1,2,1); MM(x2,y2,2,2); MM(x2,y3,2,3); \
  MM(x3,y0,3,0); MM(x3,y1,3,1); MM(x3,y2,3,2); MM(x3,y3,3,3); }while(0)

template<int MODE>
__global__ __launch_bounds__(256) void gemm_dr(
    const bf16* __restrict__ A, const bf16* __restrict__ Bw,
    bf16* __restrict__ out, float* __restrict__ outF,
    const float* __restrict__ bias1, const float* __restrict__ bias2,
    const int* __restrict__ adj, const bf16* __restrict__ xpad,
    int lda, int ldb, int kb, int ktot, int v, int tailw)
{
  const int tid  = threadIdx.x;
  const int rb0  = blockIdx.x*64;
  const int w    = tid >> 6, lane = tid & 63;
  const int quad = lane >> 4, l15 = lane & 15;
  const int n0w  = blockIdx.y*256 + w*64;

  const bf16* pA0 = A + (size_t)(rb0 + l15)*lda + quad*8;
  const bf16* pA1 = pA0 + (size_t)16*lda;
  const bf16* pA2 = pA0 + (size_t)32*lda;
  const bf16* pA3 = pA0 + (size_t)48*lda;
  const bf16* pB0 = Bw + (size_t)(n0w + l15)*ldb + quad*8;
  const bf16* pB1 = pB0 + (size_t)16*ldb;
  const bf16* pB2 = pB0 + (size_t)32*ldb;
  const bf16* pB3 = pB0 + (size_t)48*ldb;

  f32x4 acc[4][4] = {};
  bf16x8 a0,a1,a2,a3,b0,b1,b2,b3;        // current step frags
  bf16x8 p0,p1,p2,p3,q0,q1,q2,q3;        // prefetch frags

  int k = kb;
  const int nk = (ktot - kb) >> 5;
  LOADALL(a0,a1,a2,a3,b0,b1,b2,b3, k);
  if (nk & 1){                            // odd step count: peel one step
    MFMA16(a0,a1,a2,a3,b0,b1,b2,b3);
    k += 32;
    if (k < ktot) LOADALL(a0,a1,a2,a3,b0,b1,b2,b3, k);
  }
  for (; k + 32 < ktot; k += 64){         // pairs: even/odd named buffers
    LOADALL(p0,p1,p2,p3,q0,q1,q2,q3, k+32);
    MFMA16(a0,a1,a2,a3,b0,b1,b2,b3);
    if (k + 64 < ktot) LOADALL(a0,a1,a2,a3,b0,b1,b2,b3, k+64);
    MFMA16(p0,p1,p2,p3,q0,q1,q2,q3);
  }

  if (MODE == 1 || MODE == 2){
    #pragma unroll
    for (int tm=0;tm<4;++tm)
      #pragma unroll
      for (int tn=0;tn<4;++tn)
        #pragma unroll
        for (int i=0;i<4;++i){
          int b = rb0 + tm*16 + quad*4 + i;
          int c = n0w + tn*16 + l15;
          float val = acc[tm][tn][i];
          if (MODE == 1){
            out[((size_t)(c>>10)*BATCH + b)*HD + (c & 1023)] = f2bf(val);
          } else {
            if (c < 256){
              outF[(size_t)b*256 + c] = val + bias1[c];
            } else {
              val += bias2[c-256];
              val = fmaxf(val,0.f) + log1pf(__expf(-fabsf(val)));   // softplus
              outF[(size_t)BATCH*256 + (size_t)b*256 + (c-256)] = val;
            }
          }
        }
    return;
  }

  // ---- MODE 0: GRU epilogue. Block tile 64 x 256 gate-cols -> 64 h-cols.
  __shared__ __align__(16) bf16 S[64*264];   // 33 KB
  #pragma unroll
  for (int tm=0;tm<4;++tm)
    #pragma unroll
    for (int tn=0;tn<4;++tn)
      #pragma unroll
      for (int i=0;i<4;++i){
        int r = tm*16 + quad*4 + i;
        int c = w*64 + tn*16 + l15;
        S[r*264 + c] = f2bf(acc[tm][tn][i]);
      }
  __syncthreads();
  {
    const int row = tid >> 2;               // 0..63
    const int hs  = (tid & 3)*16;           // 16 h-cols per thread
    const int b   = rb0 + row;
    const int hb  = blockIdx.y*64;
    bf16 hv[16];
    #pragma unroll
    for (int j4=0; j4<16; j4+=4){
      const int hg = hb + hs + j4;
      float4 bir = *reinterpret_cast<const float4*>(bias1 + hg);
      float4 biz = *reinterpret_cast<const float4*>(bias1 + 1024 + hg);
      float4 bin = *reinterpret_cast<const float4*>(bias1 + 2048 + hg);
      float4 bhr = *reinterpret_cast<const float4*>(bias2 + hg);
      float4 bhz = *reinterpret_cast<const float4*>(bias2 + 1024 + hg);
      float4 bhn = *reinterpret_cast<const float4*>(bias2 + 2048 + hg);
      const float* p_ir = &bir.x; const float* p_iz = &biz.x; const float* p_in = &bin.x;
      const float* p_hr = &bhr.x; const float* p_hz = &bhz.x; const float* p_hn = &bhn.x;
      float ho[4];
      ld4f(A + (size_t)b*lda + hg, ho);     // h_old = first 1024 cols of A
      #pragma unroll
      for (int jj=0; jj<4; ++jj){
        float g[4];
        ld4f(&S[row*264 + (hs + j4 + jj)*4], g);   // gates r,z,hn,inn
        float r = sigm(g[0] + p_ir[jj] + p_hr[jj]);
        float z = sigm(g[1] + p_iz[jj] + p_hz[jj]);
        float n = tanhf(g[3] + p_in[jj] + r*(g[2] + p_hn[jj]));
        hv[j4+jj] = f2bf((1.f - z)*n + z*ho[jj]);
      }
    }
    uint4* dst = reinterpret_cast<uint4*>(out + (size_t)b*lda + hb + hs);
    dst[0] = *reinterpret_cast<const uint4*>(&hv[0]);
    dst[1] = *reinterpret_cast<const uint4*>(&hv[8]);
  }
  // self-masked x-tail for the NEXT GEMM (GRU-l), written once (by==0)
  if (tailw && blockIdx.y == 0){
    const int b = rb0 + (tid>>2), f0 = (tid&3)*8;
    bool self = adj[b*49 + v*8] > 0;
    uint4 tv = {0u,0u,0u,0u};
    if (self) tv = *reinterpret_cast<const uint4*>(xpad + (size_t)b*32 + f0);
    *reinterpret_cast<uint4*>(out + (size_t)b*lda + 1024 + f0) = tv;
  }
}

// ---------------------------------------------------------------------------
extern "C" void kernel_launch(void* const* d_in, const int* in_sizes, int n_in,
                              void* d_out, int out_size, void* d_ws, size_t ws_size,
                              hipStream_t stream)
{
  const float* X    = (const float*)d_in[0];
  const int*   adj  = (const int*)  d_in[1];
  const float* Wihc = (const float*)d_in[2];
  const float* Whhc = (const float*)d_in[3];
  const float* bihc = (const float*)d_in[4];
  const float* bhhc = (const float*)d_in[5];
  const float* Wihl = (const float*)d_in[6];
  const float* Whhl = (const float*)d_in[7];
  const float* bihl = (const float*)d_in[8];
  const float* bhhl = (const float*)d_in[9];
  const float* Wihr = (const float*)d_in[10];
  const float* Whhr = (const float*)d_in[11];
  const float* bihr = (const float*)d_in[12];
  const float* bhhr = (const float*)d_in[13];
  const float* Wg   = (const float*)d_in[14];
  const float* bg   = (const float*)d_in[15];
  const float* Wm   = (const float*)d_in[16];
  const float* Wmu  = (const float*)d_in[17];
  const float* bmu  = (const float*)d_in[18];
  const float* Wstd = (const float*)d_in[19];
  const float* bstd = (const float*)d_in[20];
  float* out = (float*)d_out;

  // Workspace (bf16 elems, all 16B-aligned)
  bf16* P    = (bf16*)d_ws;                      // 24*BH (6 nodes x 4 planes)
  bf16* Hin  = P    + 24*BH;                     // 2048*1056
  bf16* Hva  = Hin  + (size_t)BATCH*LDA;
  bf16* Hvb  = Hva  + (size_t)BATCH*LDA;
  bf16* Wca  = Hvb  + (size_t)BATCH*LDA;         // 4096*1056 (gate-interleaved)
  bf16* Wla  = Wca  + (size_t)4096*LDA;
  bf16* Wra  = Wla  + (size_t)4096*LDA;
  bf16* Wgm  = Wra  + (size_t)4096*LDA;          // 4096*1024
  bf16* Wms  = Wgm  + (size_t)4096*1024;         // 512*1024
  bf16* Xp   = Wms  + (size_t)512*1024;          // 7*2048*32
  bf16* XpR  = Xp   + (size_t)7*BATCH*32;        // 2048*32

  pack_waug_i<<<4096, 256, 0, stream>>>(Whhc, Wihc, 27, Wca);
  pack_waug_i<<<4096, 256, 0, stream>>>(Whhl, Wihl, 27, Wla);
  pack_waug_i<<<4096, 256, 0, stream>>>(Whhr, Wihr, 23, Wra);
  pack_wgm  <<<4096, 256, 0, stream>>>(Wg, Wm, Wgm);
  pack_wms  <<<512,  256, 0, stream>>>(Wmu, Wstd, Wms);
  pack_xpad <<<1792, 256, 0, stream>>>(X, Xp);
  pack_xpr  <<<256,  256, 0, stream>>>(X, XpR);

  for (int v=6; v>=1; --v){
    const bf16* xt = Xp + (size_t)v*BATCH*32;
    combine_k<<<1024, 256, 0, stream>>>(P, adj, bg, xt, Hin, v);
    // GRU-c (v==6: h==0 -> only the x-tail K-step, kb=1024)
    gemm_dr<0><<<dim3(32,16), 256, 0, stream>>>(Hin, Wca, Hva, nullptr,
        bihc, bhhc, adj, xt, LDA, LDA, (v==6)?1024:0, 1056, v, 1);
    // GRU-l (x tail in Hva was self-loop-masked by GRU-c's epilogue)
    gemm_dr<0><<<dim3(32,16), 256, 0, stream>>>(Hva, Wla, Hvb, nullptr,
        bihl, bhhl, adj, nullptr, LDA, LDA, 0, 1056, v, 0);
    // P projections for node v
    gemm_dr<1><<<dim3(32,16), 256, 0, stream>>>(Hvb, Wgm, P + (size_t)(v-1)*4*BH,
        nullptr, nullptr, nullptr, nullptr, nullptr, LDA, 1024, 0, 1024, 0, 0);
  }
  combine_k<<<1024, 256, 0, stream>>>(P, adj, bg, XpR, Hin, 0);
  gemm_dr<0><<<dim3(32,16), 256, 0, stream>>>(Hin, Wra, Hva, nullptr,
      bihr, bhhr, adj, nullptr, LDA, LDA, 0, 1056, 0, 0);
  gemm_dr<2><<<dim3(32,2), 256, 0, stream>>>(Hva, Wms, nullptr, out,
      bmu, bstd, nullptr, nullptr, LDA, 1024, 0, 1024, 0, 0);
}

// Round 9
// 931.301 us; speedup vs baseline: 1.1758x; 1.1758x over previous
//
#include <hip/hip_runtime.h>
#include <hip/hip_bf16.h>
#include <cmath>

// DXVAE: 7-node sequential graph GRU + VAE head, B=2048, H=1024. f32 I/O.
// R9 GEMM ("hybrid"): 64M x 256N block, 4 waves, wave = 64x64 (4x4 MFMA).
//  - A tile (64x32): single-buffer LDS staging via global_load_lds, the
//    PROVEN R6 2-barrier-per-step protocol (DMA -> barrier -> ds_read).
//  - B frags: PROVEN R7 direct 16B global->register per-step loads (no
//    cross-step prefetch, no runtime-indexed register arrays).
//  - Wave tile 64x64 gives 4x frag reuse -> LDS port no longer saturated
//    (R6's 64x32 tile was LDS-port-bound at ~30% MFMA by construction).
// GRU fused into epilogue via gate-interleaved W_aug (row = h*4+gate),
// epilogue/grids copied verbatim from R7 (passed).

typedef __hip_bfloat16 bf16;
typedef __attribute__((ext_vector_type(8))) short bf16x8;   // 8 bf16 (4 VGPRs)
typedef __attribute__((ext_vector_type(4))) float f32x4;    // C/D frag

constexpr int BATCH = 2048;
constexpr int HD    = 1024;
constexpr int LDA   = 1056;          // augmented A stride (1024 h + 32 x-pad)
constexpr size_t BH = (size_t)BATCH * HD;

__device__ __forceinline__ bf16  f2bf(float v){ return __float2bfloat16(v); }
__device__ __forceinline__ float sigm(float x){ return 1.0f/(1.0f+__expf(-x)); }

__device__ __forceinline__ void async16(bf16* lds_wave_uniform, const bf16* g){
  __builtin_amdgcn_global_load_lds(
      (const __attribute__((address_space(1))) void*)g,
      (__attribute__((address_space(3))) void*)lds_wave_uniform, 16, 0, 0);
}
// 4 bf16 -> 4 f32 (exact: bits<<16)
__device__ __forceinline__ void ld4f(const bf16* p, float* o){
  ushort4 u = *reinterpret_cast<const ushort4*>(p);
  o[0] = __uint_as_float(((unsigned)u.x)<<16);
  o[1] = __uint_as_float(((unsigned)u.y)<<16);
  o[2] = __uint_as_float(((unsigned)u.z)<<16);
  o[3] = __uint_as_float(((unsigned)u.w)<<16);
}
__device__ __forceinline__ void st4bf(bf16* p, const float* v){
  bf16 o[4] = {f2bf(v[0]), f2bf(v[1]), f2bf(v[2]), f2bf(v[3])};
  *reinterpret_cast<ushort4*>(p) = *reinterpret_cast<const ushort4*>(o);
}

// ---------------------------------------------------------------------------
// Weight packing (once per launch)
// ---------------------------------------------------------------------------
// Gate-interleaved W_aug (4096 x 1056): row h*4+g.
// g0:[Whh_r|Wih_r] g1:[Whh_z|Wih_z] g2:[Whh_n|0] g3:[0|Wih_n]; x zero-padded.
__global__ __launch_bounds__(256) void pack_waug_i(
    const float* __restrict__ Whh, const float* __restrict__ Wih, int xw,
    bf16* __restrict__ out)
{
  int c = blockIdx.x;                 // 0..4095
  int h = c >> 2, g = c & 3;
  for (int ch = threadIdx.x; ch < 264; ch += 256){
    int f0 = ch*4;
    float v[4] = {0.f,0.f,0.f,0.f};
    if (f0 < 1024){
      if (g < 3){
        int src = (g==2) ? (2048+h) : (g*1024+h);
        const float4 t = *reinterpret_cast<const float4*>(Whh + (size_t)src*1024 + f0);
        v[0]=t.x; v[1]=t.y; v[2]=t.z; v[3]=t.w;
      }
    } else if (g != 2){
      int src = (g==0) ? h : (g==1) ? (1024+h) : (2048+h);
      int fx = f0 - 1024;
      #pragma unroll
      for (int j=0;j<4;++j) if (fx+j < xw) v[j] = Wih[(size_t)src*xw + fx + j];
    }
    st4bf(out + (size_t)c*LDA + f0, v);
  }
}

// Wgm (4096x1024) = [Wg[:,:1024]; Wg[:,1024:]; Wm[:,:1024]; Wm[:,1024:]]
__global__ __launch_bounds__(256) void pack_wgm(const float* __restrict__ Wg,
    const float* __restrict__ Wm, bf16* __restrict__ outW){
  int i = blockIdx.x*256 + threadIdx.x;          // < 4096*256
  int c = i >> 8, f0 = (i & 255)*4;
  int j = c >> 10, h = c & 1023;
  const float* src = (j < 2) ? Wg : Wm;
  float4 t = *reinterpret_cast<const float4*>(src + (size_t)h*2048 + ((j & 1) ? 1024 : 0) + f0);
  float v[4] = {t.x,t.y,t.z,t.w};
  st4bf(outW + (size_t)c*1024 + f0, v);
}

// Wms (512x1024) = [Wmu; Wstd]
__global__ __launch_bounds__(256) void pack_wms(const float* __restrict__ Wmu,
    const float* __restrict__ Wstd, bf16* __restrict__ outW){
  int i = blockIdx.x*256 + threadIdx.x;          // < 512*256
  int c = i >> 8, f0 = (i & 255)*4;
  const float* src = (c < 256) ? (Wmu + (size_t)c*1024) : (Wstd + (size_t)(c-256)*1024);
  float4 t = *reinterpret_cast<const float4*>(src + f0);
  float v[4] = {t.x,t.y,t.z,t.w};
  st4bf(outW + (size_t)c*1024 + f0, v);
}

// Xpad (7 x 2048 x 32): X[:,v,:27] zero-padded to 32, bf16
__global__ __launch_bounds__(256) void pack_xpad(const float* __restrict__ X,
    bf16* __restrict__ out){
  int i = blockIdx.x*256 + threadIdx.x;          // < 7*2048*32
  int f = i & 31, bv = i >> 5;
  int b = bv / 7, v = bv % 7;
  float val = (f < 27) ? X[((size_t)b*7 + v)*27 + f] : 0.f;
  out[((size_t)v*BATCH + b)*32 + f] = f2bf(val);
}
// XpadR (2048 x 32): X[:,0,:23] zero-padded, bf16
__global__ __launch_bounds__(256) void pack_xpr(const float* __restrict__ X,
    bf16* __restrict__ out){
  int i = blockIdx.x*256 + threadIdx.x;          // < 2048*32
  int f = i & 31, b = i >> 5;
  float val = (f < 23) ? X[(size_t)b*7*27 + f] : 0.f;
  out[(size_t)b*32 + f] = f2bf(val);
}

// ---------------------------------------------------------------------------
// Stage combine: Hin[b, 0:1024] = sum_{k>v} sigm(p*Pg1+s*Pg2+bg)*(p*Pm1+s*Pm2)
// Hin[b, 1024:1056] = x-tail. v==6: empty loop -> zeros + tail.
// ---------------------------------------------------------------------------
__global__ __launch_bounds__(256) void combine_k(
    const bf16* __restrict__ P, const int* __restrict__ adj,
    const float* __restrict__ bg, const bf16* __restrict__ tailsrc,
    bf16* __restrict__ Hin, int v)
{
  int t  = threadIdx.x;
  int b  = blockIdx.x*2 + (t>>7);
  int tl = t & 127;
  int h0 = tl*8;
  float acc[8] = {0,0,0,0,0,0,0,0};
  float bgv[8];
  { const float4 a = *reinterpret_cast<const float4*>(bg + h0);
    const float4 c = *reinterpret_cast<const float4*>(bg + h0 + 4);
    bgv[0]=a.x;bgv[1]=a.y;bgv[2]=a.z;bgv[3]=a.w;bgv[4]=c.x;bgv[5]=c.y;bgv[6]=c.z;bgv[7]=c.w; }
  for (int k=v+1;k<7;++k){
    bool p = adj[b*49 + k*7 + v] > 0;
    bool s = adj[b*49 + v*7 + k] > 0;
    if (!p && !s) continue;
    const bf16* base = P + (size_t)(k-1)*4*BH + (size_t)b*HD + h0;
    float g1[8], g2[8], m1[8], m2[8];
    ld4f(base,          g1); ld4f(base+4,        g1+4);
    ld4f(base+BH,       g2); ld4f(base+BH+4,     g2+4);
    ld4f(base+2*BH,     m1); ld4f(base+2*BH+4,   m1+4);
    ld4f(base+3*BH,     m2); ld4f(base+3*BH+4,   m2+4);
    #pragma unroll
    for (int u=0;u<8;++u){
      float gg = (p?g1[u]:0.f) + (s?g2[u]:0.f);
      float mm = (p?m1[u]:0.f) + (s?m2[u]:0.f);
      acc[u] += sigm(gg + bgv[u]) * mm;
    }
  }
  st4bf(Hin + (size_t)b*LDA + h0,     acc);
  st4bf(Hin + (size_t)b*LDA + h0 + 4, acc+4);
  if (tl < 4){   // x-tail: 32 elems per row, 4 threads x 8
    const ushort4* s0 = reinterpret_cast<const ushort4*>(tailsrc + (size_t)b*32 + tl*8);
    ushort4* d0 = reinterpret_cast<ushort4*>(Hin + (size_t)b*LDA + 1024 + tl*8);
    d0[0] = s0[0]; d0[1] = s0[1];
  }
}

// ---------------------------------------------------------------------------
// Hybrid GEMM: C = A(2048 x K) @ W^T. Block 64M x 256N, 4 waves, wave 64x64.
// Per BK=32 step: wave stages 16 A-rows via 1 async16 (R6 protocol), loads
// 4 B-frags direct global->reg (R7), barrier, 4 ds_read A-frags, 16 MFMA,
// barrier. Grid (32, N/256).
// MODE 0: gate-interleaved GRU (N=4096): epilogue h' via LDS gather.
// MODE 1: P-plane output (N=4096, plane-major rows)
// MODE 2: mu/std head (N=512, f32 out, bias+softplus)
// ---------------------------------------------------------------------------
#define MM(ar,bc,i,j) acc[i][j] = __builtin_amdgcn_mfma_f32_16x16x32_bf16(ar, bc, acc[i][j], 0,0,0)

template<int MODE>
__global__ __launch_bounds__(256, 2) void gemm_h(
    const bf16* __restrict__ A, const bf16* __restrict__ Bw,
    bf16* __restrict__ out, float* __restrict__ outF,
    const float* __restrict__ bias1, const float* __restrict__ bias2,
    const int* __restrict__ adj, const bf16* __restrict__ xpad,
    int lda, int ldb, int kb, int ktot, int v, int tailw)
{
  __shared__ __align__(16) bf16 As[2048];      // A tile 64x32 (single buffer)
  __shared__ __align__(16) bf16 S[64*264];     // MODE0 epilogue staging
  const int tid  = threadIdx.x;
  const int rb0  = blockIdx.x*64;
  const int w    = tid >> 6, lane = tid & 63;
  const int quad = lane >> 4, l15 = lane & 15;
  const int sr   = lane >> 2, sc = (lane & 3)*8;
  const int n0w  = blockIdx.y*256 + w*64;

  const bf16* gA  = A + (size_t)(rb0 + w*16 + sr)*lda + sc;   // wave stages 16 rows
  const bf16* pB0 = Bw + (size_t)(n0w + l15)*ldb + quad*8;
  const bf16* pB1 = pB0 + (size_t)16*ldb;
  const bf16* pB2 = pB0 + (size_t)32*ldb;
  const bf16* pB3 = pB0 + (size_t)48*ldb;
  bf16* lA = As + w*512;                        // wave-uniform LDS dest

  f32x4 acc[4][4] = {};
  for (int k = kb; k < ktot; k += 32){
    async16(lA, gA + k);                        // A DMA (drained at barrier)
    bf16x8 b0 = *reinterpret_cast<const bf16x8*>(pB0 + k);
    bf16x8 b1 = *reinterpret_cast<const bf16x8*>(pB1 + k);
    bf16x8 b2 = *reinterpret_cast<const bf16x8*>(pB2 + k);
    bf16x8 b3 = *reinterpret_cast<const bf16x8*>(pB3 + k);
    __syncthreads();                            // all 4 waves' A-chunks landed
    bf16x8 af0 = *reinterpret_cast<const bf16x8*>(&As[(     l15)*32 + quad*8]);
    bf16x8 af1 = *reinterpret_cast<const bf16x8*>(&As[(16 + l15)*32 + quad*8]);
    bf16x8 af2 = *reinterpret_cast<const bf16x8*>(&As[(32 + l15)*32 + quad*8]);
    bf16x8 af3 = *reinterpret_cast<const bf16x8*>(&As[(48 + l15)*32 + quad*8]);
    MM(af0,b0,0,0); MM(af0,b1,0,1); MM(af0,b2,0,2); MM(af0,b3,0,3);
    MM(af1,b0,1,0); MM(af1,b1,1,1); MM(af1,b2,1,2); MM(af1,b3,1,3);
    MM(af2,b0,2,0); MM(af2,b1,2,1); MM(af2,b2,2,2); MM(af2,b3,2,3);
    MM(af3,b0,3,0); MM(af3,b1,3,1); MM(af3,b2,3,2); MM(af3,b3,3,3);
    __syncthreads();                            // As reuse guard
  }

  if (MODE == 1 || MODE == 2){
    #pragma unroll
    for (int tm=0;tm<4;++tm)
      #pragma unroll
      for (int tn=0;tn<4;++tn)
        #pragma unroll
        for (int i=0;i<4;++i){
          int b = rb0 + tm*16 + quad*4 + i;
          int c = n0w + tn*16 + l15;
          float val = acc[tm][tn][i];
          if (MODE == 1){
            out[((size_t)(c>>10)*BATCH + b)*HD + (c & 1023)] = f2bf(val);
          } else {
            if (c < 256){
              outF[(size_t)b*256 + c] = val + bias1[c];
            } else {
              val += bias2[c-256];
              val = fmaxf(val,0.f) + log1pf(__expf(-fabsf(val)));   // softplus
              outF[(size_t)BATCH*256 + (size_t)b*256 + (c-256)] = val;
            }
          }
        }
    return;
  }

  // ---- MODE 0: GRU epilogue (R7-verbatim). 256 gate-cols -> 64 h-cols.
  #pragma unroll
  for (int tm=0;tm<4;++tm)
    #pragma unroll
    for (int tn=0;tn<4;++tn)
      #pragma unroll
      for (int i=0;i<4;++i){
        int r = tm*16 + quad*4 + i;
        int c = w*64 + tn*16 + l15;
        S[r*264 + c] = f2bf(acc[tm][tn][i]);
      }
  __syncthreads();
  {
    const int row = tid >> 2;               // 0..63
    const int hs  = (tid & 3)*16;           // 16 h-cols per thread
    const int b   = rb0 + row;
    const int hb  = blockIdx.y*64;
    bf16 hv[16];
    #pragma unroll
    for (int j4=0; j4<16; j4+=4){
      const int hg = hb + hs + j4;
      float4 bir = *reinterpret_cast<const float4*>(bias1 + hg);
      float4 biz = *reinterpret_cast<const float4*>(bias1 + 1024 + hg);
      float4 bin = *reinterpret_cast<const float4*>(bias1 + 2048 + hg);
      float4 bhr = *reinterpret_cast<const float4*>(bias2 + hg);
      float4 bhz = *reinterpret_cast<const float4*>(bias2 + 1024 + hg);
      float4 bhn = *reinterpret_cast<const float4*>(bias2 + 2048 + hg);
      const float* p_ir = &bir.x; const float* p_iz = &biz.x; const float* p_in = &bin.x;
      const float* p_hr = &bhr.x; const float* p_hz = &bhz.x; const float* p_hn = &bhn.x;
      float ho[4];
      ld4f(A + (size_t)b*lda + hg, ho);     // h_old = first 1024 cols of A
      #pragma unroll
      for (int jj=0; jj<4; ++jj){
        float g[4];
        ld4f(&S[row*264 + (hs + j4 + jj)*4], g);   // gates r,z,hn,inn
        float r = sigm(g[0] + p_ir[jj] + p_hr[jj]);
        float z = sigm(g[1] + p_iz[jj] + p_hz[jj]);
        float n = tanhf(g[3] + p_in[jj] + r*(g[2] + p_hn[jj]));
        hv[j4+jj] = f2bf((1.f - z)*n + z*ho[jj]);
      }
    }
    uint4* dst = reinterpret_cast<uint4*>(out + (size_t)b*lda + hb + hs);
    dst[0] = *reinterpret_cast<const uint4*>(&hv[0]);
    dst[1] = *reinterpret_cast<const uint4*>(&hv[8]);
  }
  // self-masked x-tail for the NEXT GEMM (GRU-l), written once (by==0)
  if (tailw && blockIdx.y == 0){
    const int b = rb0 + (tid>>2), f0 = (tid&3)*8;
    bool self = adj[b*49 + v*8] > 0;
    uint4 tv = {0u,0u,0u,0u};
    if (self) tv = *reinterpret_cast<const uint4*>(xpad + (size_t)b*32 + f0);
    *reinterpret_cast<uint4*>(out + (size_t)b*lda + 1024 + f0) = tv;
  }
}

// ---------------------------------------------------------------------------
extern "C" void kernel_launch(void* const* d_in, const int* in_sizes, int n_in,
                              void* d_out, int out_size, void* d_ws, size_t ws_size,
                              hipStream_t stream)
{
  const float* X    = (const float*)d_in[0];
  const int*   adj  = (const int*)  d_in[1];
  const float* Wihc = (const float*)d_in[2];
  const float* Whhc = (const float*)d_in[3];
  const float* bihc = (const float*)d_in[4];
  const float* bhhc = (const float*)d_in[5];
  const float* Wihl = (const float*)d_in[6];
  const float* Whhl = (const float*)d_in[7];
  const float* bihl = (const float*)d_in[8];
  const float* bhhl = (const float*)d_in[9];
  const float* Wihr = (const float*)d_in[10];
  const float* Whhr = (const float*)d_in[11];
  const float* bihr = (const float*)d_in[12];
  const float* bhhr = (const float*)d_in[13];
  const float* Wg   = (const float*)d_in[14];
  const float* bg   = (const float*)d_in[15];
  const float* Wm   = (const float*)d_in[16];
  const float* Wmu  = (const float*)d_in[17];
  const float* bmu  = (const float*)d_in[18];
  const float* Wstd = (const float*)d_in[19];
  const float* bstd = (const float*)d_in[20];
  float* out = (float*)d_out;

  // Workspace (bf16 elems, all 16B-aligned)
  bf16* P    = (bf16*)d_ws;                      // 24*BH (6 nodes x 4 planes)
  bf16* Hin  = P    + 24*BH;                     // 2048*1056
  bf16* Hva  = Hin  + (size_t)BATCH*LDA;
  bf16* Hvb  = Hva  + (size_t)BATCH*LDA;
  bf16* Wca  = Hvb  + (size_t)BATCH*LDA;         // 4096*1056 (gate-interleaved)
  bf16* Wla  = Wca  + (size_t)4096*LDA;
  bf16* Wra  = Wla  + (size_t)4096*LDA;
  bf16* Wgm  = Wra  + (size_t)4096*LDA;          // 4096*1024
  bf16* Wms  = Wgm  + (size_t)4096*1024;         // 512*1024
  bf16* Xp   = Wms  + (size_t)512*1024;          // 7*2048*32
  bf16* XpR  = Xp   + (size_t)7*BATCH*32;        // 2048*32

  pack_waug_i<<<4096, 256, 0, stream>>>(Whhc, Wihc, 27, Wca);
  pack_waug_i<<<4096, 256, 0, stream>>>(Whhl, Wihl, 27, Wla);
  pack_waug_i<<<4096, 256, 0, stream>>>(Whhr, Wihr, 23, Wra);
  pack_wgm  <<<4096, 256, 0, stream>>>(Wg, Wm, Wgm);
  pack_wms  <<<512,  256, 0, stream>>>(Wmu, Wstd, Wms);
  pack_xpad <<<1792, 256, 0, stream>>>(X, Xp);
  pack_xpr  <<<256,  256, 0, stream>>>(X, XpR);

  for (int v=6; v>=1; --v){
    const bf16* xt = Xp + (size_t)v*BATCH*32;
    combine_k<<<1024, 256, 0, stream>>>(P, adj, bg, xt, Hin, v);
    // GRU-c (v==6: h==0 -> only the x-tail K-step, kb=1024)
    gemm_h<0><<<dim3(32,16), 256, 0, stream>>>(Hin, Wca, Hva, nullptr,
        bihc, bhhc, adj, xt, LDA, LDA, (v==6)?1024:0, 1056, v, 1);
    // GRU-l (x tail in Hva was self-loop-masked by GRU-c's epilogue)
    gemm_h<0><<<dim3(32,16), 256, 0, stream>>>(Hva, Wla, Hvb, nullptr,
        bihl, bhhl, adj, nullptr, LDA, LDA, 0, 1056, v, 0);
    // P projections for node v
    gemm_h<1><<<dim3(32,16), 256, 0, stream>>>(Hvb, Wgm, P + (size_t)(v-1)*4*BH,
        nullptr, nullptr, nullptr, nullptr, nullptr, LDA, 1024, 0, 1024, 0, 0);
  }
  combine_k<<<1024, 256, 0, stream>>>(P, adj, bg, XpR, Hin, 0);
  gemm_h<0><<<dim3(32,16), 256, 0, stream>>>(Hin, Wra, Hva, nullptr,
      bihr, bhhr, adj, nullptr, LDA, LDA, 0, 1056, 0, 0);
  gemm_h<2><<<dim3(32,2), 256, 0, stream>>>(Hva, Wms, nullptr, out,
      bmu, bstd, nullptr, nullptr, LDA, 1024, 0, 1024, 0, 0);
}

// Round 10
// 820.010 us; speedup vs baseline: 1.3353x; 1.1357x over previous
//
#include <hip/hip_runtime.h>
#include <hip/hip_bf16.h>
#include <cmath>

// DXVAE: 7-node sequential graph GRU + VAE head, B=2048, H=1024. f32 I/O.
// R10 = R6 (proven 840us champion: 64x128-tile, global_load_lds width-16,
// 2-barrier K-loop, 1024 blocks = 4/CU) + ONE change: bijective XCD-aware
// block swizzle. Native round-robin gives each XCD ALL by values -> per-XCD
// B working set 8.6MB >> 4MB L2 -> B refetched ~3.5x at HBM latency inside
// the barrier drain. Swizzle gives each XCD a 16bx x 8by rectangle ->
// A 2.2MB + B 2.2MB fits L2 -> reuse at L2-hit latency.
// GRU fused into the GEMM epilogue via gate-interleaved W_aug (row=h*4+gate).

typedef __hip_bfloat16 bf16;
typedef __attribute__((ext_vector_type(8))) short bf16x8;   // 8 bf16 (4 VGPRs)
typedef __attribute__((ext_vector_type(4))) float f32x4;    // C/D frag

constexpr int BATCH = 2048;
constexpr int HD    = 1024;
constexpr int LDA   = 1056;          // augmented A stride (1024 h + 32 x-pad)
constexpr size_t BH = (size_t)BATCH * HD;

__device__ __forceinline__ bf16  f2bf(float v){ return __float2bfloat16(v); }
__device__ __forceinline__ float sigm(float x){ return 1.0f/(1.0f+__expf(-x)); }

__device__ __forceinline__ void async16(bf16* lds_wave_uniform, const bf16* g){
  __builtin_amdgcn_global_load_lds(
      (const __attribute__((address_space(1))) void*)g,
      (__attribute__((address_space(3))) void*)lds_wave_uniform, 16, 0, 0);
}
// 4 bf16 -> 4 f32 (exact: bits<<16)
__device__ __forceinline__ void ld4f(const bf16* p, float* o){
  ushort4 u = *reinterpret_cast<const ushort4*>(p);
  o[0] = __uint_as_float(((unsigned)u.x)<<16);
  o[1] = __uint_as_float(((unsigned)u.y)<<16);
  o[2] = __uint_as_float(((unsigned)u.z)<<16);
  o[3] = __uint_as_float(((unsigned)u.w)<<16);
}
__device__ __forceinline__ void st4bf(bf16* p, const float* v){
  bf16 o[4] = {f2bf(v[0]), f2bf(v[1]), f2bf(v[2]), f2bf(v[3])};
  *reinterpret_cast<ushort4*>(p) = *reinterpret_cast<const ushort4*>(o);
}

// ---------------------------------------------------------------------------
// Weight packing (once per launch)
// ---------------------------------------------------------------------------
// Gate-interleaved W_aug (4096 x 1056): row h*4+g.
// g0:[Whh_r|Wih_r] g1:[Whh_z|Wih_z] g2:[Whh_n|0] g3:[0|Wih_n]; x zero-padded.
__global__ __launch_bounds__(256) void pack_waug_i(
    const float* __restrict__ Whh, const float* __restrict__ Wih, int xw,
    bf16* __restrict__ out)
{
  int c = blockIdx.x;                 // 0..4095
  int h = c >> 2, g = c & 3;
  for (int ch = threadIdx.x; ch < 264; ch += 256){
    int f0 = ch*4;
    float v[4] = {0.f,0.f,0.f,0.f};
    if (f0 < 1024){
      if (g < 3){
        int src = (g==2) ? (2048+h) : (g*1024+h);
        const float4 t = *reinterpret_cast<const float4*>(Whh + (size_t)src*1024 + f0);
        v[0]=t.x; v[1]=t.y; v[2]=t.z; v[3]=t.w;
      }
    } else if (g != 2){
      int src = (g==0) ? h : (g==1) ? (1024+h) : (2048+h);
      int fx = f0 - 1024;
      #pragma unroll
      for (int j=0;j<4;++j) if (fx+j < xw) v[j] = Wih[(size_t)src*xw + fx + j];
    }
    st4bf(out + (size_t)c*LDA + f0, v);
  }
}

// Wgm (4096x1024) = [Wg[:,:1024]; Wg[:,1024:]; Wm[:,:1024]; Wm[:,1024:]]
__global__ __launch_bounds__(256) void pack_wgm(const float* __restrict__ Wg,
    const float* __restrict__ Wm, bf16* __restrict__ outW){
  int i = blockIdx.x*256 + threadIdx.x;          // < 4096*256
  int c = i >> 8, f0 = (i & 255)*4;
  int j = c >> 10, h = c & 1023;
  const float* src = (j < 2) ? Wg : Wm;
  float4 t = *reinterpret_cast<const float4*>(src + (size_t)h*2048 + ((j & 1) ? 1024 : 0) + f0);
  float v[4] = {t.x,t.y,t.z,t.w};
  st4bf(outW + (size_t)c*1024 + f0, v);
}

// Wms (512x1024) = [Wmu; Wstd]
__global__ __launch_bounds__(256) void pack_wms(const float* __restrict__ Wmu,
    const float* __restrict__ Wstd, bf16* __restrict__ outW){
  int i = blockIdx.x*256 + threadIdx.x;          // < 512*256
  int c = i >> 8, f0 = (i & 255)*4;
  const float* src = (c < 256) ? (Wmu + (size_t)c*1024) : (Wstd + (size_t)(c-256)*1024);
  float4 t = *reinterpret_cast<const float4*>(src + f0);
  float v[4] = {t.x,t.y,t.z,t.w};
  st4bf(outW + (size_t)c*1024 + f0, v);
}

// Xpad (7 x 2048 x 32): X[:,v,:27] zero-padded to 32, bf16
__global__ __launch_bounds__(256) void pack_xpad(const float* __restrict__ X,
    bf16* __restrict__ out){
  int i = blockIdx.x*256 + threadIdx.x;          // < 7*2048*32
  int f = i & 31, bv = i >> 5;
  int b = bv / 7, v = bv % 7;
  float val = (f < 27) ? X[((size_t)b*7 + v)*27 + f] : 0.f;
  out[((size_t)v*BATCH + b)*32 + f] = f2bf(val);
}
// XpadR (2048 x 32): X[:,0,:23] zero-padded, bf16
__global__ __launch_bounds__(256) void pack_xpr(const float* __restrict__ X,
    bf16* __restrict__ out){
  int i = blockIdx.x*256 + threadIdx.x;          // < 2048*32
  int f = i & 31, b = i >> 5;
  float val = (f < 23) ? X[(size_t)b*7*27 + f] : 0.f;
  out[(size_t)b*32 + f] = f2bf(val);
}

// ---------------------------------------------------------------------------
// Stage combine: Hin[b, 0:1024] = sum_{k>v} sigm(p*Pg1+s*Pg2+bg)*(p*Pm1+s*Pm2)
// Hin[b, 1024:1056] = x-tail. v==6: empty loop -> zeros + tail.
// ---------------------------------------------------------------------------
__global__ __launch_bounds__(256) void combine_k(
    const bf16* __restrict__ P, const int* __restrict__ adj,
    const float* __restrict__ bg, const bf16* __restrict__ tailsrc,
    bf16* __restrict__ Hin, int v)
{
  int t  = threadIdx.x;
  int b  = blockIdx.x*2 + (t>>7);
  int tl = t & 127;
  int h0 = tl*8;
  float acc[8] = {0,0,0,0,0,0,0,0};
  float bgv[8];
  { const float4 a = *reinterpret_cast<const float4*>(bg + h0);
    const float4 c = *reinterpret_cast<const float4*>(bg + h0 + 4);
    bgv[0]=a.x;bgv[1]=a.y;bgv[2]=a.z;bgv[3]=a.w;bgv[4]=c.x;bgv[5]=c.y;bgv[6]=c.z;bgv[7]=c.w; }
  for (int k=v+1;k<7;++k){
    bool p = adj[b*49 + k*7 + v] > 0;
    bool s = adj[b*49 + v*7 + k] > 0;
    if (!p && !s) continue;
    const bf16* base = P + (size_t)(k-1)*4*BH + (size_t)b*HD + h0;
    float g1[8], g2[8], m1[8], m2[8];
    ld4f(base,          g1); ld4f(base+4,        g1+4);
    ld4f(base+BH,       g2); ld4f(base+BH+4,     g2+4);
    ld4f(base+2*BH,     m1); ld4f(base+2*BH+4,   m1+4);
    ld4f(base+3*BH,     m2); ld4f(base+3*BH+4,   m2+4);
    #pragma unroll
    for (int u=0;u<8;++u){
      float gg = (p?g1[u]:0.f) + (s?g2[u]:0.f);
      float mm = (p?m1[u]:0.f) + (s?m2[u]:0.f);
      acc[u] += sigm(gg + bgv[u]) * mm;
    }
  }
  st4bf(Hin + (size_t)b*LDA + h0,     acc);
  st4bf(Hin + (size_t)b*LDA + h0 + 4, acc+4);
  if (tl < 4){   // x-tail: 32 elems per row, 4 threads x 8
    const ushort4* s0 = reinterpret_cast<const ushort4*>(tailsrc + (size_t)b*32 + tl*8);
    ushort4* d0 = reinterpret_cast<ushort4*>(Hin + (size_t)b*LDA + 1024 + tl*8);
    d0[0] = s0[0]; d0[1] = s0[1];
  }
}

// ---------------------------------------------------------------------------
// 64x128-tile GEMM, m97-style staging (R6-verbatim K-loop). C = A(2048xK)@W^T.
// 4 waves, wave w owns N-cols [w*32, w*32+32): B wave-private (2 async16),
// A shared across waves (1 async16 each staging 16 rows). BK=32.
// Per block-step: 32 MFMA, 12 KB staged, 2 barriers.
// swz=1: flat grid 1024, bijective XCD swizzle (xcd=id&7 -> 16bx x 8by
// rectangle per XCD). swz=0: plain 2-D grid.
// MODE 0: gate-interleaved GRU (N=4096): epilogue h' via LDS gather.
// MODE 1: P-plane output (N=4096, plane-major rows)
// MODE 2: mu/std head (N=512, f32 out, bias+softplus)
// ---------------------------------------------------------------------------
template<int MODE>
__global__ __launch_bounds__(256) void gemm_t(
    const bf16* __restrict__ A, const bf16* __restrict__ Bw,
    bf16* __restrict__ out, float* __restrict__ outF,
    const float* __restrict__ bias1, const float* __restrict__ bias2,
    const int* __restrict__ adj, const bf16* __restrict__ xpad,
    int lda, int ldb, int kb, int ktot, int v, int tailw, int swz)
{
  // 8704 bf16 = 17.4 KB; staging uses [0,6144): As 64x32, Bs 4x(32x32).
  __shared__ __align__(16) bf16 S[64*136];
  bf16* As = S;
  bf16* Bs = S + 2048;
  const int tid  = threadIdx.x;
  int bx, by;
  if (swz){ int xcd = blockIdx.x & 7, s = blockIdx.x >> 3;   // s in [0,128)
    bx = ((xcd & 1) << 4) | (s & 15);                        // [0,32)
    by = ((xcd >> 1) << 3) | (s >> 4);                       // [0,32)
  } else { bx = blockIdx.x; by = blockIdx.y; }
  const int rb0  = bx*64, n0 = by*128;
  const int lane = tid & 63, w = tid >> 6;
  const int quad = lane >> 4, l15 = lane & 15;
  const int sr   = lane >> 2, sc = (lane & 3)*8;   // staging lane -> row/col

  // staging sources (lane-resolved); dest base is wave-uniform (HW adds lane*16)
  const bf16* gA = A  + (size_t)(rb0 + w*16 + sr)*lda + sc;
  const bf16* gB = Bw + (size_t)(n0  + w*32 + sr)*ldb + sc;
  bf16* lA = As + w*512;      // wave w stages A rows [w*16, w*16+16)
  bf16* lB = Bs + w*1024;     // wave w's private B tile (32x32)

  f32x4 acc[4][2] = {};
  for (int k0 = kb; k0 < ktot; k0 += 32){
    async16(lA,       gA + k0);
    async16(lB,       gB + k0);
    async16(lB + 512, gB + k0 + (size_t)16*ldb);
    __syncthreads();
    bf16x8 af0 = *reinterpret_cast<const bf16x8*>(&As[(  0 + l15)*32 + quad*8]);
    bf16x8 af1 = *reinterpret_cast<const bf16x8*>(&As[( 16 + l15)*32 + quad*8]);
    bf16x8 af2 = *reinterpret_cast<const bf16x8*>(&As[( 32 + l15)*32 + quad*8]);
    bf16x8 af3 = *reinterpret_cast<const bf16x8*>(&As[( 48 + l15)*32 + quad*8]);
    bf16x8 bf0 = *reinterpret_cast<const bf16x8*>(&Bs[w*1024 + (     l15)*32 + quad*8]);
    bf16x8 bf1 = *reinterpret_cast<const bf16x8*>(&Bs[w*1024 + (16 + l15)*32 + quad*8]);
    acc[0][0] = __builtin_amdgcn_mfma_f32_16x16x32_bf16(af0, bf0, acc[0][0], 0,0,0);
    acc[0][1] = __builtin_amdgcn_mfma_f32_16x16x32_bf16(af0, bf1, acc[0][1], 0,0,0);
    acc[1][0] = __builtin_amdgcn_mfma_f32_16x16x32_bf16(af1, bf0, acc[1][0], 0,0,0);
    acc[1][1] = __builtin_amdgcn_mfma_f32_16x16x32_bf16(af1, bf1, acc[1][1], 0,0,0);
    acc[2][0] = __builtin_amdgcn_mfma_f32_16x16x32_bf16(af2, bf0, acc[2][0], 0,0,0);
    acc[2][1] = __builtin_amdgcn_mfma_f32_16x16x32_bf16(af2, bf1, acc[2][1], 0,0,0);
    acc[3][0] = __builtin_amdgcn_mfma_f32_16x16x32_bf16(af3, bf0, acc[3][0], 0,0,0);
    acc[3][1] = __builtin_amdgcn_mfma_f32_16x16x32_bf16(af3, bf1, acc[3][1], 0,0,0);
    __syncthreads();
  }

  if (MODE == 1 || MODE == 2){
    #pragma unroll
    for (int tm=0;tm<4;++tm)
      #pragma unroll
      for (int tn=0;tn<2;++tn)
        #pragma unroll
        for (int i=0;i<4;++i){
          int b = rb0 + tm*16 + quad*4 + i;
          int c = n0  + w*32 + tn*16 + l15;
          float val = acc[tm][tn][i];
          if (MODE == 1){
            out[((size_t)(c>>10)*BATCH + b)*HD + (c & 1023)] = f2bf(val);
          } else {
            if (c < 256){
              outF[(size_t)b*256 + c] = val + bias1[c];
            } else {
              val += bias2[c-256];
              val = fmaxf(val,0.f) + log1pf(__expf(-fabsf(val)));   // softplus
              outF[(size_t)BATCH*256 + (size_t)b*256 + (c-256)] = val;
            }
          }
        }
    return;
  }

  // ---- MODE 0: GRU epilogue. Stage acc tile (64x128) to LDS, gather gates.
  #pragma unroll
  for (int tm=0;tm<4;++tm)
    #pragma unroll
    for (int tn=0;tn<2;++tn)
      #pragma unroll
      for (int i=0;i<4;++i){
        int r = tm*16 + quad*4 + i;
        int c = w*32 + tn*16 + l15;
        S[r*136 + c] = f2bf(acc[tm][tn][i]);
      }
  __syncthreads();
  {
    const int row = tid >> 2;                 // 0..63
    const int hs  = (tid & 3)*8;              // 0,8,16,24 (h within block's 32)
    const int b   = rb0 + row;
    const int hbase = by*32;
    bf16 hv[16];  // only 8 used; padded for uint4 stores
    #pragma unroll
    for (int j4=0; j4<8; j4+=4){
      const int hg = hbase + hs + j4;
      float4 bir = *reinterpret_cast<const float4*>(bias1 + hg);
      float4 biz = *reinterpret_cast<const float4*>(bias1 + 1024 + hg);
      float4 bin = *reinterpret_cast<const float4*>(bias1 + 2048 + hg);
      float4 bhr = *reinterpret_cast<const float4*>(bias2 + hg);
      float4 bhz = *reinterpret_cast<const float4*>(bias2 + 1024 + hg);
      float4 bhn = *reinterpret_cast<const float4*>(bias2 + 2048 + hg);
      const float* p_ir = &bir.x; const float* p_iz = &biz.x; const float* p_in = &bin.x;
      const float* p_hr = &bhr.x; const float* p_hz = &bhz.x; const float* p_hn = &bhn.x;
      float ho[4];
      ld4f(A + (size_t)b*lda + hg, ho);       // h_old = first 1024 cols of A
      #pragma unroll
      for (int jj=0; jj<4; ++jj){
        float g[4];
        ld4f(&S[row*136 + (hs + j4 + jj)*4], g);   // gates r,z,hn,inn
        float r = sigm(g[0] + p_ir[jj] + p_hr[jj]);
        float z = sigm(g[1] + p_iz[jj] + p_hz[jj]);
        float n = tanhf(g[3] + p_in[jj] + r*(g[2] + p_hn[jj]));
        hv[j4+jj] = f2bf((1.f - z)*n + z*ho[jj]);
      }
    }
    *reinterpret_cast<uint4*>(out + (size_t)b*lda + hbase + hs) =
        *reinterpret_cast<const uint4*>(&hv[0]);
  }
  // self-masked x-tail for the NEXT GEMM (GRU-l), written once (by==0)
  if (tailw && by == 0){
    const int b = rb0 + (tid>>2), f0 = (tid&3)*8;
    bool self = adj[b*49 + v*8] > 0;
    uint4 tv = {0u,0u,0u,0u};
    if (self) tv = *reinterpret_cast<const uint4*>(xpad + (size_t)b*32 + f0);
    *reinterpret_cast<uint4*>(out + (size_t)b*lda + 1024 + f0) = tv;
  }
}

// ---------------------------------------------------------------------------
extern "C" void kernel_launch(void* const* d_in, const int* in_sizes, int n_in,
                              void* d_out, int out_size, void* d_ws, size_t ws_size,
                              hipStream_t stream)
{
  const float* X    = (const float*)d_in[0];
  const int*   adj  = (const int*)  d_in[1];
  const float* Wihc = (const float*)d_in[2];
  const float* Whhc = (const float*)d_in[3];
  const float* bihc = (const float*)d_in[4];
  const float* bhhc = (const float*)d_in[5];
  const float* Wihl = (const float*)d_in[6];
  const float* Whhl = (const float*)d_in[7];
  const float* bihl = (const float*)d_in[8];
  const float* bhhl = (const float*)d_in[9];
  const float* Wihr = (const float*)d_in[10];
  const float* Whhr = (const float*)d_in[11];
  const float* bihr = (const float*)d_in[12];
  const float* bhhr = (const float*)d_in[13];
  const float* Wg   = (const float*)d_in[14];
  const float* bg   = (const float*)d_in[15];
  const float* Wm   = (const float*)d_in[16];
  const float* Wmu  = (const float*)d_in[17];
  const float* bmu  = (const float*)d_in[18];
  const float* Wstd = (const float*)d_in[19];
  const float* bstd = (const float*)d_in[20];
  float* out = (float*)d_out;

  // Workspace (bf16 elems, all 16B-aligned)
  bf16* P    = (bf16*)d_ws;                      // 24*BH (6 nodes x 4 planes)
  bf16* Hin  = P    + 24*BH;                     // 2048*1056
  bf16* Hva  = Hin  + (size_t)BATCH*LDA;
  bf16* Hvb  = Hva  + (size_t)BATCH*LDA;
  bf16* Wca  = Hvb  + (size_t)BATCH*LDA;         // 4096*1056 (gate-interleaved)
  bf16* Wla  = Wca  + (size_t)4096*LDA;
  bf16* Wra  = Wla  + (size_t)4096*LDA;
  bf16* Wgm  = Wra  + (size_t)4096*LDA;          // 4096*1024
  bf16* Wms  = Wgm  + (size_t)4096*1024;         // 512*1024
  bf16* Xp   = Wms  + (size_t)512*1024;          // 7*2048*32
  bf16* XpR  = Xp   + (size_t)7*BATCH*32;        // 2048*32

  pack_waug_i<<<4096, 256, 0, stream>>>(Whhc, Wihc, 27, Wca);
  pack_waug_i<<<4096, 256, 0, stream>>>(Whhl, Wihl, 27, Wla);
  pack_waug_i<<<4096, 256, 0, stream>>>(Whhr, Wihr, 23, Wra);
  pack_wgm  <<<4096, 256, 0, stream>>>(Wg, Wm, Wgm);
  pack_wms  <<<512,  256, 0, stream>>>(Wmu, Wstd, Wms);
  pack_xpad <<<1792, 256, 0, stream>>>(X, Xp);
  pack_xpr  <<<256,  256, 0, stream>>>(X, XpR);

  for (int v=6; v>=1; --v){
    const bf16* xt = Xp + (size_t)v*BATCH*32;
    combine_k<<<1024, 256, 0, stream>>>(P, adj, bg, xt, Hin, v);
    // GRU-c (v==6: h==0 -> only the x-tail K-step, kb=1024)
    gemm_t<0><<<1024, 256, 0, stream>>>(Hin, Wca, Hva, nullptr,
        bihc, bhhc, adj, xt, LDA, LDA, (v==6)?1024:0, 1056, v, 1, 1);
    // GRU-l (x tail in Hva was self-loop-masked by GRU-c's epilogue)
    gemm_t<0><<<1024, 256, 0, stream>>>(Hva, Wla, Hvb, nullptr,
        bihl, bhhl, adj, nullptr, LDA, LDA, 0, 1056, v, 0, 1);
    // P projections for node v
    gemm_t<1><<<1024, 256, 0, stream>>>(Hvb, Wgm, P + (size_t)(v-1)*4*BH,
        nullptr, nullptr, nullptr, nullptr, nullptr, LDA, 1024, 0, 1024, 0, 0, 1);
  }
  combine_k<<<1024, 256, 0, stream>>>(P, adj, bg, XpR, Hin, 0);
  gemm_t<0><<<1024, 256, 0, stream>>>(Hin, Wra, Hva, nullptr,
      bihr, bhhr, adj, nullptr, LDA, LDA, 0, 1056, 0, 0, 1);
  gemm_t<2><<<dim3(32,4), 256, 0, stream>>>(Hva, Wms, nullptr, out,
      bmu, bstd, nullptr, nullptr, LDA, 1024, 0, 1024, 0, 0, 0);
}